// Round 8
// baseline (479.754 us; speedup 1.0000x reference)
//
#include <hip/hip_runtime.h>
#include <hip/hip_bf16.h>
#include <cstdint>
#include <cstddef>

// WideLSTM: N=32 blocks, I=64, H=128, B=16, T=256.
// 128 WGs = 32 blocks x 4 batch-groups, 1024 thr = 16 waves = 4 waves/SIMD.
// R8: R2 K-split pair skeleton with x fully on the STORE-FREE partner wave
// via a global->register ring (no xbuf, no gx workspace, single kernel):
//   wave w (0..7):   Whh k[0,64) (8 MFMA, 2-deep from bias cb), epilogue,
//                    h/out writes.  Pure-LDS + stores; no global loads in loop.
//   wave w+8:        phase1: Whh k[64,128) (8 MFMA, 2-deep CHAINED from the
//                    carried x-acc -> exchange rides the C-operand), partial
//                    pre-selected -> pbuf.  phase2 (under w's epilogue chain):
//                    convert reg-ring x(S+1) -> frags, 8 Wih MFMA -> xacc(S+2
//                    consumer), reload ring <- x(S+2).  Partner has NO stores,
//                    so vmcnt stays clean (R4 lesson); 1-step slack ~1550cyc
//                    >> 900cyc HBM latency (R7 gx-ring proved the pattern).
// LDS/step/CU: 40 b128 reads + 16 writes (~490 cyc) vs R2's 736.
// MFMA 930/SIMD, 310 of it in phase2 hidden under the ~350cyc epilogue chain.
// 2 lgkm-only barriers/step; no setprio (R5 evidence); c register-resident.

#define TSTEPS 256

typedef float  f32x4  __attribute__((ext_vector_type(4)));
typedef float  f32x2  __attribute__((ext_vector_type(2)));
typedef __bf16 bf16x8 __attribute__((ext_vector_type(8)));
typedef short  s16x8  __attribute__((ext_vector_type(8)));

union Frag { s16x8 s; bf16x8 b; };

#define KSIG -1.4426950408889634f   // -1/ln2 (sigmoid)
#define KTAN  2.8853900817779268f   //  2/ln2 (tanh)

__device__ __forceinline__ short f2bf(float f) {
  uint32_t u = __builtin_bit_cast(uint32_t, f);
  u += 0x7fffu + ((u >> 16) & 1u);
  return (short)(u >> 16);
}

// lgkm-only barrier: global loads/stores stay in flight across it
__device__ __forceinline__ void sync_lds() {
  asm volatile("s_waitcnt lgkmcnt(0)" ::: "memory");
  __builtin_amdgcn_s_barrier();
  asm volatile("" ::: "memory");
}

__device__ __forceinline__ float sig2(float z) {   // rcp(1 + exp2(z))
  return __builtin_amdgcn_rcpf(1.f + __builtin_amdgcn_exp2f(z));
}

__device__ __forceinline__ f32x4 mf(const Frag a, const Frag bb, f32x4 c) {
  return __builtin_amdgcn_mfma_f32_16x16x32_bf16(a.b, bb.b, c, 0, 0, 0);
}

__device__ __forceinline__ float sel4(const f32x4 a, bool m1, bool m2) {
  const float u01 = m1 ? a[1] : a[0];
  const float u23 = m1 ? a[3] : a[2];
  return m2 ? u23 : u01;
}

__global__ __launch_bounds__(1024, 4) void wide_lstm(
    const float* __restrict__ x,   const float* __restrict__ h0,
    const float* __restrict__ c0,  const float* __restrict__ wih,
    const float* __restrict__ whh, const float* __restrict__ bih,
    const float* __restrict__ bhh, float* __restrict__ out)
{
  const int n    = blockIdx.x & 31;
  const int bg   = blockIdx.x >> 5;      // batch group: batches [4bg, 4bg+4)
  const int tid  = threadIdx.x;
  const int wv   = tid >> 6;             // wave 0..15
  const int w    = wv & 7;               // pair id / h-tile [16w, 16w+16)
  const bool isw = (wv < 8);             // front half: epilogue owner
  const int lane = tid & 63;
  const int col  = lane & 15;
  const int quad = lane >> 4;
  const int b4   = col & 3;              // batch within group
  const int e2   = col >> 2;             // acc row r this lane keeps (0..3)
  const int hloc = 4 * quad + e2;
  const int hgl  = 16 * w + hloc;        // h within block (0..127)
  const int b    = 4 * bg + b4;          // global batch this lane updates

  // h: 4 rows x stride 144 shorts (bank-tuned, measured 0 conflicts)
  __shared__ alignas(16) short hbuf[2][4 * 144];
  // pair-exchange partials: one f32x4 per partner lane, contiguous b128.
  // WAR-safe single-buffered: written phase1(S), read phase2(S), next write
  // phase1(S+1) is after A'(S).
  __shared__ alignas(16) float pbuf[8][64][4];

  const int hoff  = b4 * 144 + quad * 8;     // h B-frag base
  const int hwoff = b4 * 144 + hgl;          // h write slot
  const bool m1 = (e2 & 1), m2 = (e2 & 2);
  const f32x4 kzero = (f32x4){0.f, 0.f, 0.f, 0.f};

  // ---- Whh fragments (both roles): w: k0=32sl; partner: k0=64+32sl ----
  Frag wfr[2][4];
#pragma unroll
  for (int j = 0; j < 4; ++j) {
    const int g = 128 * j + 16 * w + col;
#pragma unroll
    for (int sl = 0; sl < 2; ++sl) {
      const int k0 = (isw ? 32 * sl : 64 + 32 * sl) + quad * 8;
      const float* p = whh + (size_t)(n * 512 + g) * 128 + k0;
      const f32x4 lo = *(const f32x4*)p;
      const f32x4 hi = *(const f32x4*)(p + 4);
      Frag f;
      f.s[0]=f2bf(lo[0]); f.s[1]=f2bf(lo[1]); f.s[2]=f2bf(lo[2]); f.s[3]=f2bf(lo[3]);
      f.s[4]=f2bf(hi[0]); f.s[5]=f2bf(hi[1]); f.s[6]=f2bf(hi[2]); f.s[7]=f2bf(hi[3]);
      wfr[sl][j] = f;
    }
  }

  if (isw) {
    // ================= epilogue-owner waves =================
    f32x4 cb[4];
#pragma unroll
    for (int j = 0; j < 4; ++j) {
      const int base = n * 512 + 128 * j + 16 * w + quad * 4;
      const f32x4 b1 = *(const f32x4*)(bih + base);
      const f32x4 b2 = *(const f32x4*)(bhh + base);
#pragma unroll
      for (int r = 0; r < 4; ++r) cb[j][r] = b1[r] + b2[r];
    }
    if (tid < 256) {
      const int bi = tid >> 6, j2 = (tid & 63) * 2;
      const f32x2 hv = *(const f32x2*)(h0 + (size_t)(4 * bg + bi) * 4096 + n * 128 + j2);
      *(uint32_t*)&hbuf[0][bi * 144 + j2] =
          (uint32_t)(uint16_t)f2bf(hv[0]) | ((uint32_t)(uint16_t)f2bf(hv[1]) << 16);
    }
    float cg = c0[(size_t)b * 4096 + n * 128 + hgl];
    float* outp = out + (size_t)b * (TSTEPS * 4096) + n * 128 + hgl;
    float ho = 0.f;
    __syncthreads();   // h(0) staged, partner xacc(0) ready

#define WSTEP(CUR, NXT)                                                      \
  {                                                                          \
    Frag hf0, hf1;                                                           \
    hf0.s = *(const s16x8*)&hbuf[CUR][hoff];                                 \
    hf1.s = *(const s16x8*)&hbuf[CUR][hoff + 32];                            \
    f32x4 ac1[4];                                                            \
    _Pragma("unroll") for (int j = 0; j < 4; ++j)                            \
      ac1[j] = mf(wfr[1][j], hf1, mf(wfr[0][j], hf0, cb[j]));                \
    float pre[4];                                                            \
    _Pragma("unroll") for (int j = 0; j < 4; ++j)                            \
      pre[j] = sel4(ac1[j], m1, m2);                                         \
    sync_lds(); /* B: partner partial (k[64,128) + x-proj) ready */          \
    const f32x4 vv = *(const f32x4*)&pbuf[w][lane][0];                       \
    pre[0] += vv[0]; pre[1] += vv[1]; pre[2] += vv[2]; pre[3] += vv[3];      \
    const float si = sig2(KSIG * pre[0]);                                    \
    const float sf = sig2(KSIG * pre[1]);                                    \
    const float sg = sig2(KTAN * pre[2]);                                    \
    const float so = sig2(KSIG * pre[3]);                                    \
    float cn = __builtin_fmaf(sf, cg, si);                                   \
    cn = __builtin_fmaf(-2.f, si * sg, cn);                                  \
    cg = cn;                                                                 \
    ho = so * __builtin_fmaf(-2.f, sig2(KTAN * cn), 1.f);                    \
    hbuf[NXT][hwoff] = f2bf(ho);                                             \
    *outp = ho;                                                              \
    outp += 4096;                                                            \
    sync_lds(); /* A' */                                                     \
  }
    for (int t = 0; t < TSTEPS; t += 2) {
      WSTEP(0, 1);
      WSTEP(1, 0);
    }
#undef WSTEP
    // ---- h_n / c_n (one float per w lane) ----
    out[16777216 +         (size_t)b * 4096 + n * 128 + hgl] = ho;
    out[16777216 + 65536 + (size_t)b * 4096 + n * 128 + hgl] = cg;

  } else {
    // ================= partner waves (store-free) =================
    // Wih fragments
    Frag wfx[2][4];
#pragma unroll
    for (int j = 0; j < 4; ++j) {
      const int g = 128 * j + 16 * w + col;
#pragma unroll
      for (int sl = 0; sl < 2; ++sl) {
        const float* p = wih + (size_t)(n * 512 + g) * 64 + 32 * sl + quad * 8;
        const f32x4 lo = *(const f32x4*)p;
        const f32x4 hi = *(const f32x4*)(p + 4);
        Frag f;
        f.s[0]=f2bf(lo[0]); f.s[1]=f2bf(lo[1]); f.s[2]=f2bf(lo[2]); f.s[3]=f2bf(lo[3]);
        f.s[4]=f2bf(hi[0]); f.s[5]=f2bf(hi[1]); f.s[6]=f2bf(hi[2]); f.s[7]=f2bf(hi[3]);
        wfx[sl][j] = f;
      }
    }
    // per-lane x source for this lane's B-frag floats (batch b)
    const float* xb = x + (size_t)b * (TSTEPS * 2048) + n * 64 + 8 * quad;

    // xacc(0) = Wih * x(0), fragged direct from global (one-time)
    f32x4 xacc[4];
    {
      const f32x4 a0 = *(const f32x4*)xb;
      const f32x4 a1 = *(const f32x4*)(xb + 4);
      const f32x4 a2 = *(const f32x4*)(xb + 32);
      const f32x4 a3 = *(const f32x4*)(xb + 36);
      Frag xf0, xf1;
#pragma unroll
      for (int r = 0; r < 4; ++r) {
        xf0.b[r]     = (__bf16)a0[r];
        xf0.b[4 + r] = (__bf16)a1[r];
        xf1.b[r]     = (__bf16)a2[r];
        xf1.b[4 + r] = (__bf16)a3[r];
      }
#pragma unroll
      for (int j = 0; j < 4; ++j)
        xacc[j] = mf(wfx[1][j], xf1, mf(wfx[0][j], xf0, kzero));
    }
    // ring slot <- x(1); consumed phase2 of step 0; ~1 step in flight
    f32x4 rx0, rx1, rx2, rx3;
    {
      const float* p1 = xb + 2048;
      rx0 = *(const f32x4*)p1;        rx1 = *(const f32x4*)(p1 + 4);
      rx2 = *(const f32x4*)(p1 + 32); rx3 = *(const f32x4*)(p1 + 36);
    }
    __syncthreads();

    // Step S: phase1: hf2,hf3 reads -> 8 Whh MFMA chained from xacc(S)
    //         -> sel -> pbuf.  [B]  phase2: convert rx (= x(S+1)) -> frags,
    //         8 Wih MFMA -> xacc(S+1); reload rx <- x(S+2).  [A']
#define PSTEP(CUR, NXT, S)                                                   \
  {                                                                          \
    Frag hf2, hf3;                                                           \
    hf2.s = *(const s16x8*)&hbuf[CUR][hoff + 64];                            \
    hf3.s = *(const s16x8*)&hbuf[CUR][hoff + 96];                            \
    f32x4 ac[4];                                                             \
    _Pragma("unroll") for (int j = 0; j < 4; ++j)                            \
      ac[j] = mf(wfr[1][j], hf3, mf(wfr[0][j], hf2, xacc[j]));               \
    f32x4 vv;                                                                \
    vv[0] = sel4(ac[0], m1, m2);                                             \
    vv[1] = sel4(ac[1], m1, m2);                                             \
    vv[2] = sel4(ac[2], m1, m2);                                             \
    vv[3] = sel4(ac[3], m1, m2);                                             \
    *(f32x4*)&pbuf[w][lane][0] = vv;                                         \
    sync_lds(); /* B */                                                      \
    Frag xg0, xg1;                                                           \
    _Pragma("unroll") for (int r = 0; r < 4; ++r) {                          \
      xg0.b[r]     = (__bf16)rx0[r];                                         \
      xg0.b[4 + r] = (__bf16)rx1[r];                                         \
      xg1.b[r]     = (__bf16)rx2[r];                                         \
      xg1.b[4 + r] = (__bf16)rx3[r];                                         \
    }                                                                        \
    _Pragma("unroll") for (int j = 0; j < 4; ++j)                            \
      xacc[j] = mf(wfx[0][j], xg0, kzero);                                   \
    _Pragma("unroll") for (int j = 0; j < 4; ++j)                            \
      xacc[j] = mf(wfx[1][j], xg1, xacc[j]);                                 \
    {                                                                        \
      const int tt = ((S) + 2 < TSTEPS) ? (S) + 2 : (TSTEPS - 1);            \
      const float* p2 = xb + (size_t)tt * 2048;                              \
      rx0 = *(const f32x4*)p2;        rx1 = *(const f32x4*)(p2 + 4);         \
      rx2 = *(const f32x4*)(p2 + 32); rx3 = *(const f32x4*)(p2 + 36);        \
    }                                                                        \
    sync_lds(); /* A' */                                                     \
  }
    for (int t = 0; t < TSTEPS; t += 2) {
      PSTEP(0, 1, t);
      PSTEP(1, 0, t + 1);
    }
#undef PSTEP
  }
}

extern "C" void kernel_launch(void* const* d_in, const int* in_sizes, int n_in,
                              void* d_out, int out_size, void* d_ws, size_t ws_size,
                              hipStream_t stream) {
  const float* x   = (const float*)d_in[0];
  const float* h0  = (const float*)d_in[1];
  const float* c0  = (const float*)d_in[2];
  const float* wih = (const float*)d_in[3];
  const float* whh = (const float*)d_in[4];
  const float* bih = (const float*)d_in[5];
  const float* bhh = (const float*)d_in[6];
  float* out = (float*)d_out;
  wide_lstm<<<128, 1024, 0, stream>>>(x, h0, c0, wih, whh, bih, bhh, out);
}